// Round 10
// baseline (37007.507 us; speedup 1.0000x reference)
//
#include <hip/hip_runtime.h>
#include <math.h>

// ---------------- problem constants ----------------
#define BB 8
#define TT 512
#define LL 20
#define NBLK 64
#define NTHR 256

typedef float f4 __attribute__((ext_vector_type(4)));
typedef unsigned long long ull;

__constant__ int c_dil[LL] = {1,2,4,8,16,32,64,128,256,512,
                              1,2,4,8,16,32,64,128,256,512};
// double-buffered rings: layer l has 2*d slots of 1024 floats (ring[0] unused)
__constant__ int c_roff[LL] = {-1,0,4096,12288,28672,61440,126976,258048,520192,1044480,
                               2093056,2095104,2099200,2107392,2123776,2156544,
                               2222080,2353152,2615296,3139584};

// ---------------- workspace layout (floats) ----------------
constexpr size_t OFF_RING = 0;          // 4,188,160 floats
constexpr size_t OFF_X    = 4188160;    // exchange: 4 slots * 512 float4

// ---------------- LDS pool offsets (floats) ----------------
#define P_WC     0        // [20][4][256] (l=0 slice UNUSED -> overlaid by P_TB)
#define P_TB     0        // [256][4]: {U, C1, A0, KP} layer-0 closed form, all rows
#define P_F      20480    // [19][4][128]
#define P_CZ0    30208    // [256][8]: per-chunk layer-0 z base (KC+biases+cond.c)
#define P_KC     32256    // [256]
#define P_WST    32512    // [512]
#define P_WF0    33024    // [128]
#define P_WF1    33152    // [128]
#define P_FB     33280    // [128]
#define P_CONDZ  33408    // [20][4][8]
#define P_SFC    34048    // [2][8]
#define P_RESB   34064    // [20][2]
#define P_SKIPB  34104    // [20][2]
#define P_ZB     34144    // [20][4]
#define P_LOGB   34224    // [4]
#define P_SKC    34228    // [2][3]
#define P_XS     34234    // [3][8]
#define P_SL     34258    // [32]
#define P_SKACC  34290    // [16]
#define P_R2     34306    // [16]
#define P_CF     34322    // [8][66]
// pad 2 -> 34852 (16B align)
#define P_PREVF  34852    // [8][132]
#define P_HF     35908    // [2][8][132] parity
#define P_RESF   38020    // [2][8][132] parity (buf0 holds res_0 at step start)
#define POOL_FL  40132    // 160,528 bytes -> 1 block/CU

// ---------------- coherent 16B exchange primitives (sc0 sc1 -> L3) ----------
__device__ __forceinline__ f4 ldx(const f4* p) {
    f4 r;
    asm volatile("global_load_dwordx4 %0, %1, off sc0 sc1\n\ts_waitcnt vmcnt(0)"
                 : "=v"(r) : "v"(p) : "memory");
    return r;
}
__device__ __forceinline__ void ldx2(const f4* p0, const f4* p1, f4& a, f4& b) {
    asm volatile("global_load_dwordx4 %0, %2, off sc0 sc1\n\t"
                 "global_load_dwordx4 %1, %3, off sc0 sc1\n\t"
                 "s_waitcnt vmcnt(0)"
                 : "=&v"(a), "=&v"(b) : "v"(p0), "v"(p1) : "memory");
}
__device__ __forceinline__ void ld4x(const f4* a0, const f4* a1, const f4* a2, const f4* a3,
                                     f4& r0, f4& r1, f4& r2, f4& r3) {
    asm volatile("global_load_dwordx4 %0, %4, off sc0 sc1\n\t"
                 "global_load_dwordx4 %1, %5, off sc0 sc1\n\t"
                 "global_load_dwordx4 %2, %6, off sc0 sc1\n\t"
                 "global_load_dwordx4 %3, %7, off sc0 sc1\n\t"
                 "s_waitcnt vmcnt(0)"
                 : "=&v"(r0), "=&v"(r1), "=&v"(r2), "=&v"(r3)
                 : "v"(a0), "v"(a1), "v"(a2), "v"(a3) : "memory");
}
__device__ __forceinline__ void stx(f4* p, f4 v) {
    asm volatile("global_store_dwordx4 %0, %1, off sc0 sc1"
                 :: "v"(p), "v"(v) : "memory");
}
__device__ __forceinline__ void spin(const f4* p, int e, f4& a) {
    while (__float_as_int(a.w) != e) a = ldx(p);
}

// ---- uniform mailbox: 8 f4 per block per exchange; f4 q = {v(2q'), v(2q'+1), 0, tag}
// value index V = 2q+i: V<8 -> batch V, row 2*Jb; V>=8 -> batch V-8, row 2*Jb+1
__device__ __forceinline__ void pub2(f4* slot, int J, int q, float v0, float v1, int e) {
    f4 v; v.x = v0; v.y = v1; v.z = 0.f; v.w = __int_as_float(e);
    stx(slot + J*8 + q, v);
}
__device__ __forceinline__ void scat2(float* dst, f4 v, int idx, bool dorelu) {
    int Jb = idx >> 3, q = idx & 7;
    float x = v.x, y = v.y;
    if (dorelu) { x = fmaxf(x, 0.f); y = fmaxf(y, 0.f); }
    if (q < 4) {
        dst[(2*q)*132 + 2*Jb]     = x;
        dst[(2*q+1)*132 + 2*Jb]   = y;
    } else {
        dst[(2*q-8)*132 + 2*Jb+1] = x;
        dst[(2*q-7)*132 + 2*Jb+1] = y;
    }
}
__device__ __forceinline__ void consume(const f4* slot, int e, float* dst, bool dorelu) {
    int m = threadIdx.x;
    const f4 *p0 = slot + m, *p1 = slot + 256 + m;
    f4 a, b;
    ldx2(p0, p1, a, b);
    spin(p0, e, a);
    spin(p1, e, b);
    scat2(dst, a, m, dorelu);
    scat2(dst, b, m + 256, dorelu);
}
__device__ __forceinline__ void consume_pair(const f4* sR, int eR, float* dR,
                                             const f4* sH, int eH, float* dH) {
    int m = threadIdx.x;
    const f4 *pra = sR + m, *prb = sR + 256 + m, *pha = sH + m, *phb = sH + 256 + m;
    f4 ra, rb, ha, hb;
    ld4x(pra, prb, pha, phb, ra, rb, ha, hb);
    spin(pra, eR, ra);
    spin(prb, eR, rb);
    scat2(dR, ra, m, false);
    scat2(dR, rb, m + 256, false);
    spin(pha, eH, ha);
    spin(phb, eH, hb);
    scat2(dH, ha, m, false);
    scat2(dH, hb, m + 256, false);
}

// ============================================================
__global__ __launch_bounds__(NTHR, 1) void wn_gen(
    const float* __restrict__ enc,
    const float* __restrict__ first_w,  const float* __restrict__ first_b,
    const float* __restrict__ causal_w, const float* __restrict__ causal_b,
    const float* __restrict__ cond_w,   const float* __restrict__ cond_b,
    const float* __restrict__ res_w,    const float* __restrict__ res_b,
    const float* __restrict__ skip_w,   const float* __restrict__ skip_b,
    const float* __restrict__ skipc_w,  const float* __restrict__ skipc_b,
    const float* __restrict__ fc_w,     const float* __restrict__ fc_b,
    const float* __restrict__ condf_w,  const float* __restrict__ condf_b,
    const float* __restrict__ logits_w, const float* __restrict__ logits_b,
    float* __restrict__ wsf, float* __restrict__ out)
{
    extern __shared__ float pool[];
    const int tid = threadIdx.x;
    const int J = blockIdx.x;
    float* ring = wsf + OFF_RING;
    f4* xb = (f4*)(wsf + OFF_X);

    // ---------------- init phase 1: LDS staging ----------------
    for (int m = 1024 + tid; m < 20480; m += NTHR) {      // skip l=0 slice (TB overlay)
        int l = m >> 10, rem = m & 1023, g = rem >> 8, i = rem & 255;
        int grow = (g < 2) ? (2*J + g) : (128 + 2*J + (g - 2));
        int col = i & 127, k = i >> 7;
        pool[P_WC + m] = causal_w[((size_t)(l*256 + grow)*128 + col)*2 + k];
    }
    if (tid < 128) {
        pool[P_WF0 + tid] = first_w[2*tid];
        pool[P_WF1 + tid] = first_w[2*tid + 1];
        pool[P_FB + tid]  = first_b[tid];
    }
    if (tid < 40) {
        int l = tid >> 1, r = tid & 1;
        pool[P_RESB + tid]  = res_b[l*128 + 2*J + r];
        pool[P_SKIPB + tid] = skip_b[l*128 + 2*J + r];
    }
    if (tid < 4) pool[P_LOGB + tid] = logits_b[4*J + tid];
    if (tid < 8) {
        pool[P_XS + tid]      = 128.f/255.f - 0.5f;  // X(0)
        pool[P_XS + 8 + tid]  = 0.f;                 // X(-1)
        pool[P_XS + 16 + tid] = 0.f;                 // X(-2)
    }
    // register-resident weights
    float wl[16], wfc[16];
    {
        int g = (tid >> 3) & 3, k = tid & 7;
        #pragma unroll
        for (int i = 0; i < 16; ++i)
            wl[i] = logits_w[(size_t)(4*J + g)*128 + k + 8*i];
        int r2 = (tid >> 6) & 1;
        #pragma unroll
        for (int i = 0; i < 16; ++i)
            wfc[i] = fc_w[(size_t)(2*J + r2)*128 + k + 8*i];
    }
    __syncthreads();

    // ---------------- init phase 2: derived tables ----------------
    // F_l[g][j] = sum_i W1_{l+1}[g][i] * res_w[l][i][j]   (l = 0..18)
    for (int l = 0; l < 19; ++l) {
        for (int m = tid; m < 512; m += NTHR) {
            int g = m >> 7, j = m & 127;
            const float* w1 = pool + P_WC + ((l+1)*4 + g)*256 + 128;
            const float* rw = res_w + (size_t)l*128*128 + j;
            float acc = 0.f;
            #pragma unroll 8
            for (int i = 0; i < 128; ++i) acc += w1[i] * rw[(size_t)i*128];
            pool[P_F + (l*4 + g)*128 + j] = acc;
        }
    }
    // zb_l[g] = W1_l[g] . res_b[l-1]  (l >= 1)
    if (tid < 80) {
        int l = tid >> 2, g = tid & 3;
        float acc = 0.f;
        if (l >= 1) {
            const float* w1 = pool + P_WC + (l*4 + g)*256 + 128;
            for (int i = 0; i < 128; ++i) acc += w1[i] * res_b[(l-1)*128 + i];
        }
        pool[P_ZB + tid] = acc;
    }
    // TB: layer-0 closed-form coefficients for ALL 256 z-rows (from global causal_w)
    {
        int grow = tid;
        const float* cw0 = causal_w + (size_t)grow*256;   // l=0 row grow: [j*2 + k]
        float u = 0.f, c1 = 0.f, a0 = 0.f, kp = 0.f, kc = 0.f;
        for (int j = 0; j < 128; ++j) {
            float w0 = cw0[2*j], w1 = cw0[2*j + 1];
            float f0 = pool[P_WF0 + j], f1 = pool[P_WF1 + j], fbv = pool[P_FB + j];
            u  += w0*f0;  c1 += w0*f1 + w1*f0;  a0 += w1*f1;
            kp += w0*fbv; kc += w1*fbv;
        }
        pool[P_TB + grow*4 + 0] = u;
        pool[P_TB + grow*4 + 1] = c1;
        pool[P_TB + grow*4 + 2] = a0;
        pool[P_TB + grow*4 + 3] = kp;
        pool[P_KC + grow]       = kc;
    }
    // skip-init closed form: skip0 = SK + x1*SA + x0*SB  (skipc_w from global)
    if (tid < 2) {
        const float* wr = skipc_w + (size_t)(2*J + tid)*128;
        float sk = skipc_b[2*J + tid], sa = 0.f, sb = 0.f;
        for (int j = 0; j < 128; ++j) {
            sk += wr[j]*pool[P_FB + j];
            sa += wr[j]*pool[P_WF0 + j];
            sb += wr[j]*pool[P_WF1 + j];
        }
        pool[P_SKC + tid*3 + 0] = sk;
        pool[P_SKC + tid*3 + 1] = sa;
        pool[P_SKC + tid*3 + 2] = sb;
    }
    __syncthreads();

    int e = 0;            // exchange epoch (uniform across all blocks)
    int er_pending = 0;   // epoch of most recent res publish
    int esk = 0;          // epoch of skip publish

    const int w = tid >> 6, lane = tid & 63;

    for (int t = 0; t < TT; ++t) {
        // ---------------- per-chunk precompute ----------------
        if ((t & 63) == 0) {
            int te = t >> 6;
            for (int m = tid; m < 512; m += NTHR) {
                int b = m >> 6, j = m & 63;
                pool[P_CF + b*66 + j] = enc[(size_t)b*512 + j*8 + te];
            }
            __syncthreads();
            for (int m = tid; m < 640; m += NTHR) {
                int l = m >> 5, rem = m & 31, g = rem >> 3, b = rem & 7;
                int grow = (g < 2) ? (2*J + g) : (128 + 2*J + (g - 2));
                float acc = causal_b[l*256 + grow] + cond_b[l*256 + grow]
                          + pool[P_ZB + l*4 + g];
                const float* cw = cond_w + (size_t)(l*256 + grow)*64;
                const float* cf = pool + P_CF + b*66;
                for (int j = 0; j < 64; ++j) acc += cw[j]*cf[j];
                pool[P_CONDZ + l*32 + g*8 + b] = acc;
            }
            // CZ0: full layer-0 z base for all 256 rows
            {
                int grow = tid;
                float base = pool[P_KC + grow] + causal_b[grow] + cond_b[grow];
                const float* cw = cond_w + (size_t)grow*64;
                for (int b = 0; b < 8; ++b) {
                    const float* cf = pool + P_CF + b*66;
                    float acc = base;
                    for (int j = 0; j < 64; ++j) acc += cw[j]*cf[j];
                    pool[P_CZ0 + grow*8 + b] = acc;
                }
            }
            if (tid < 16) {
                int r = tid >> 3, b = tid & 7, row = 2*J + r;
                float acc = fc_b[row] + condf_b[row];
                const float* cw = condf_w + (size_t)row*64;
                const float* cf = pool + P_CF + b*66;
                for (int j = 0; j < 64; ++j) acc += cw[j]*cf[j];
                pool[P_SFC + r*8 + b] = acc;
            }
            __syncthreads();
        }

        // ---------------- step start: FULL h_0 computed locally (no exchange) ----
        {
            int j = tid & 127, bh2 = tid >> 7;
            float kf = (t >= 1) ? 1.f : 0.f;
            const float* tg = pool + P_TB + j*4;
            const float* to = pool + P_TB + (128 + j)*4;
            #pragma unroll
            for (int bb = 0; bb < 4; ++bb) {
                int b = bh2*4 + bb;
                float x0v = pool[P_XS + b], x1v = pool[P_XS + 8 + b], x2v = pool[P_XS + 16 + b];
                float zg = pool[P_CZ0 + j*8 + b]
                         + x2v*tg[0] + x1v*tg[1] + x0v*tg[2] + kf*tg[3];
                float zo = pool[P_CZ0 + (128 + j)*8 + b]
                         + x2v*to[0] + x1v*to[1] + x0v*to[2] + kf*to[3];
                pool[P_HF + b*132 + j] = (1.f/(1.f + expf(-zg))) * tanhf(zo);   // buf0
            }
        }
        // res_0 -> RESF buf0
        for (int m = tid; m < 1024; m += NTHR) {
            int b = m >> 7, r = m & 127;
            pool[P_RESF + b*132 + r] =
                pool[P_FB + r] + pool[P_XS + 8 + b]*pool[P_WF0 + r]
                               + pool[P_XS + b]    *pool[P_WF1 + r];
        }
        // skip init + r2 init (closed form)
        if (tid < 16) {
            int r = tid >> 3, b = tid & 7;
            float x0v = pool[P_XS + b], x1v = pool[P_XS + 8 + b];
            pool[P_SKACC + r*8 + b] = pool[P_SKC + r*3] + x1v*pool[P_SKC + r*3 + 1]
                                                        + x0v*pool[P_SKC + r*3 + 2];
            int row = 2*J + r;
            pool[P_R2 + r*8 + b] = pool[P_FB + row] + x1v*pool[P_WF0 + row]
                                                    + x0v*pool[P_WF1 + row];
        }

        // ---------------- layer loop: 2 barriers per layer ----------------
        for (int l = 0; l < LL; ++l) {
            const int par = l & 1;
            int ehh = 0;
            if (l >= 1) {
                // S1': full-width in-wave z -> h -> publish
                ++e; ehh = e;
                const int r = w & 1, bh = w >> 1;
                const int b2 = lane >> 4, half = (lane >> 3) & 1, k = lane & 7;
                const int b = bh*4 + b2, g = half*2 + r;
                const float* wz = pool + P_WC + (l*4 + g)*256;
                const float* fm = pool + P_F + ((l-1)*4 + g)*128;
                const float* pv = pool + P_PREVF + b*132;
                const float* rs = pool + P_RESF + (par^1)*1056 + b*132;
                const float* hh = pool + P_HF + (par^1)*1056 + b*132;
                float acc = 0.f;
                #pragma unroll
                for (int i = 0; i < 16; ++i) {
                    int j = k + 8*i;
                    acc += wz[j]*pv[j] + wz[128 + j]*rs[j] + fm[j]*hh[j];
                }
                acc += __shfl_xor(acc,1); acc += __shfl_xor(acc,2); acc += __shfl_xor(acc,4);
                acc += pool[P_CONDZ + l*32 + g*8 + b];
                float zp = __shfl_xor(acc, 8);                // partner half
                float zg = half ? zp : acc;
                float zo = half ? acc : zp;
                float h  = (1.f/(1.f + expf(-zg))) * tanhf(zo);
                float hnb = __shfl_xor(h, 16);                // neighbor b2^1
                if (half == 0 && k == 0 && (b2 & 1) == 0)
                    pub2(xb + (size_t)(ehh & 3)*512, J,
                         r*4 + bh*2 + (b2 >> 1), h, hnb, ehh);
            }
            // S6: stage res/skip weight rows (issue)
            float wv0, wv1;
            {
                int r0 = tid >> 7, i0 = tid & 127;
                wv0 = res_w [(size_t)(l*128 + 2*J + r0)*128 + i0];
                wv1 = skip_w[(size_t)(l*128 + 2*J + r0)*128 + i0];
            }
            // S7: ring prefetch prev_{l+1} (issue)
            ull pfa = 0, pfb = 0;
            if (l <= 18) {
                int d = c_dil[l+1];
                if (t >= d) {
                    int slot = (t - d) & (2*d - 1);
                    const float* rp = ring + c_roff[l+1] + (size_t)slot*1024 + tid*4;
                    pfa = __hip_atomic_load((const ull*)rp,     __ATOMIC_RELAXED, __HIP_MEMORY_SCOPE_AGENT);
                    pfb = __hip_atomic_load((const ull*)(rp+2), __ATOMIC_RELAXED, __HIP_MEMORY_SCOPE_AGENT);
                }
            }
            // S8: consume into parity buffers (l=0: h local, nothing to consume)
            if (l >= 1 && l <= 18) {
                consume_pair(xb + (size_t)(er_pending & 3)*512, er_pending,
                             pool + P_RESF + par*1056,
                             xb + (size_t)(ehh & 3)*512, ehh,
                             pool + P_HF + par*1056);
            } else if (l == 19) {
                consume(xb + (size_t)(ehh & 3)*512, ehh, pool + P_HF + par*1056, false);
            }
            // S8.5: land staged weight rows
            pool[P_WST + tid] = wv0;
            pool[P_WST + 256 + tid] = wv1;
            __syncthreads();   // bar A
            // S10: dres (waves 0,1) + skip accum (waves 2,3), in-wave publish
            {
                int b = lane >> 3, k = lane & 7;
                int r = w & 1, isSkip = w >> 1;
                if (isSkip || l <= 18) {
                    const float* wr = pool + P_WST + (isSkip ? 256 : 0) + r*128;
                    const float* hh = pool + P_HF + par*1056 + b*132;
                    float acc = 0.f;
                    #pragma unroll
                    for (int i = 0; i < 16; ++i) { int j = k + 8*i; acc += wr[j]*hh[j]; }
                    acc += __shfl_xor(acc,1); acc += __shfl_xor(acc,2); acc += __shfl_xor(acc,4);
                    if (isSkip) {
                        float v = pool[P_SKACC + r*8 + b] + acc + pool[P_SKIPB + l*2 + r];
                        if (k == 0) pool[P_SKACC + r*8 + b] = v;
                        if (l == 19) {
                            float vnb = __shfl_xor(v, 8);
                            if (k == 0 && !(b & 1))
                                pub2(xb + (size_t)((e+1) & 3)*512, J,
                                     r*4 + (b >> 1), v, vnb, e + 1);
                        }
                    } else {
                        float v = pool[P_R2 + r*8 + b] + acc + pool[P_RESB + l*2 + r];
                        if (k == 0) {
                            pool[P_R2 + r*8 + b] = v;
                            int d = c_dil[l+1];
                            int slot = t & (2*d - 1);
                            float* wp = ring + c_roff[l+1] + (size_t)slot*1024 + b*128 + 2*J + r;
                            __hip_atomic_store(wp, v, __ATOMIC_RELAXED, __HIP_MEMORY_SCOPE_AGENT);
                        }
                        if (l <= 17) {
                            float vnb = __shfl_xor(v, 8);
                            if (k == 0 && !(b & 1))
                                pub2(xb + (size_t)((e+1) & 3)*512, J,
                                     r*4 + (b >> 1), v, vnb, e + 1);
                        }
                    }
                }
            }
            // uniform epoch bookkeeping for S10 publishes
            if (l <= 17)      { ++e; er_pending = e; }
            else if (l == 19) { ++e; esk = e; }
            // S11: land prev prefetch
            if (l <= 18) {
                int b = tid >> 5, c = (tid & 31)*4;
                union { ull u; float f[2]; } u0, u1;
                u0.u = pfa; u1.u = pfb;
                float* dp = pool + P_PREVF + b*132 + c;
                dp[0] = u0.f[0]; dp[1] = u0.f[1]; dp[2] = u1.f[0]; dp[3] = u1.f[1];
            }
            __syncthreads();   // bar B
        }

        // ---------------- head ----------------
        consume(xb + (size_t)(esk & 3)*512, esk, pool + P_HF, false);   // skip -> HF buf0
        __syncthreads();
        // fc: s = relu(skip).fc^T + sfc  (waves 0,1), in-wave publish
        ++e;
        {
            int b = lane >> 3, k = lane & 7, r = w & 1;
            if (w < 2) {
                const float* sk = pool + P_HF + b*132;
                float acc = 0.f;
                #pragma unroll
                for (int i = 0; i < 16; ++i) { int j = k + 8*i; acc += wfc[i]*fmaxf(sk[j], 0.f); }
                acc += __shfl_xor(acc,1); acc += __shfl_xor(acc,2); acc += __shfl_xor(acc,4);
                float v = acc + pool[P_SFC + r*8 + b];
                float vnb = __shfl_xor(v, 8);
                if (k == 0 && !(b & 1))
                    pub2(xb + (size_t)(e & 3)*512, J, r*4 + (b >> 1), v, vnb, e);
            }
        }
        consume(xb + (size_t)(e & 3)*512, e, pool + P_RESF, true);      // relu(s) -> RESF buf0
        __syncthreads();
        // logits rows + out-store + block-local argmax pair
        {
            int b = tid >> 5, g = (tid >> 3) & 3, k = tid & 7;
            const float* sv = pool + P_RESF + b*132;
            float acc = 0.f;
            #pragma unroll
            for (int i = 0; i < 16; ++i) { int j = k + 8*i; acc += wl[i]*sv[j]; }
            acc += __shfl_xor(acc,1); acc += __shfl_xor(acc,2); acc += __shfl_xor(acc,4);
            float v = acc + pool[P_LOGB + g];
            float best = (k == 0) ? v : -3.4e38f;
            int bi = 4*J + g;
            { float ov = __shfl_xor(best, 8);  int oi = __shfl_xor(bi, 8);
              if (ov > best || (ov == best && oi < bi)) { best = ov; bi = oi; } }
            { float ov = __shfl_xor(best, 16); int oi = __shfl_xor(bi, 16);
              if (ov > best || (ov == best && oi < bi)) { best = ov; bi = oi; } }
            if (k == 0) out[4096 + ((size_t)(t*BB + b))*256 + 4*J + g] = v;
            if ((tid & 31) == 0) { pool[P_SL + 2*b] = best; pool[P_SL + 2*b + 1] = (float)bi; }
        }
        __syncthreads();
        ++e;
        // argmax pairs: P_SL = {max0,idx0,max1,idx1,...} reordered for pub2:
        // publish q<4 -> (max pairs), q>=4 -> (idx pairs)
        if (tid < 8) {
            int q = tid;
            float v0, v1;
            if (q < 4) { v0 = pool[P_SL + 4*q];     v1 = pool[P_SL + 4*q + 2]; }       // max(2q), max(2q+1)
            else       { v0 = pool[P_SL + 4*(q-4) + 1]; v1 = pool[P_SL + 4*(q-4) + 3]; } // idx(2q'), idx(2q'+1)
            pub2(xb + (size_t)(e & 3)*512, J, q, v0, v1, e);
        }
        consume(xb + (size_t)(e & 3)*512, e, pool + P_HF, false);       // -> HF buf0
        __syncthreads();
        // final argmax reduce (idx-min tie-break == global first max) + x shift
        if (tid < 64) {
            int b = tid >> 3, j0 = tid & 7;
            float best = -3.4e38f; float bidx = 0.f;
            #pragma unroll
            for (int k2 = 0; k2 < 8; ++k2) {
                int j = j0*8 + k2;
                float v  = pool[P_HF + b*132 + 2*j];
                float id = pool[P_HF + b*132 + 2*j + 1];
                if (v > best || (v == best && id < bidx)) { best = v; bidx = id; }
            }
            #pragma unroll
            for (int m = 4; m >= 1; m >>= 1) {
                float ov = __shfl_xor(best, m); float oi = __shfl_xor(bidx, m);
                if (ov > best || (ov == best && oi < bidx)) { best = ov; bidx = oi; }
            }
            if (j0 == 0) {
                if (J == 0) out[t*BB + b] = bidx;
                pool[P_XS + 16 + b] = pool[P_XS + 8 + b];
                pool[P_XS + 8 + b]  = pool[P_XS + b];
                pool[P_XS + b]      = bidx*(1.f/255.f) - 0.5f;
            }
        }
        __syncthreads();
    }
}

// ============================================================
extern "C" void kernel_launch(void* const* d_in, const int* in_sizes, int n_in,
                              void* d_out, int out_size, void* d_ws, size_t ws_size,
                              hipStream_t stream) {
    const float* enc      = (const float*)d_in[0];
    const float* first_w  = (const float*)d_in[1];
    const float* first_b  = (const float*)d_in[2];
    const float* causal_w = (const float*)d_in[3];
    const float* causal_b = (const float*)d_in[4];
    const float* cond_w   = (const float*)d_in[5];
    const float* cond_b   = (const float*)d_in[6];
    const float* res_w    = (const float*)d_in[7];
    const float* res_b    = (const float*)d_in[8];
    const float* skip_w   = (const float*)d_in[9];
    const float* skip_b   = (const float*)d_in[10];
    const float* skipc_w  = (const float*)d_in[11];
    const float* skipc_b  = (const float*)d_in[12];
    const float* fc_w     = (const float*)d_in[13];
    const float* fc_b     = (const float*)d_in[14];
    const float* condf_w  = (const float*)d_in[15];
    const float* condf_b  = (const float*)d_in[16];
    const float* logits_w = (const float*)d_in[17];
    const float* logits_b = (const float*)d_in[18];

    float* wsf = (float*)d_ws;
    float* out = (float*)d_out;

    wn_gen<<<NBLK, NTHR, POOL_FL*4, stream>>>(
        enc, first_w, first_b, causal_w, causal_b, cond_w, cond_b,
        res_w, res_b, skip_w, skip_b, skipc_w, skipc_b, fc_w, fc_b,
        condf_w, condf_b, logits_w, logits_b, wsf, out);
}

// Round 12
// 36055.701 us; speedup vs baseline: 1.0264x; 1.0264x over previous
//
#include <hip/hip_runtime.h>
#include <math.h>

// ---------------- problem constants ----------------
#define BB 8
#define TT 512
#define LL 20
#define NBLK 64
#define NTHR 512

typedef float f4 __attribute__((ext_vector_type(4)));
typedef unsigned long long ull;

__constant__ int c_dil[LL] = {1,2,4,8,16,32,64,128,256,512,
                              1,2,4,8,16,32,64,128,256,512};
// double-buffered rings: layer l has 2*d slots of 1024 floats (ring[0] unused)
__constant__ int c_roff[LL] = {-1,0,4096,12288,28672,61440,126976,258048,520192,1044480,
                               2093056,2095104,2099200,2107392,2123776,2156544,
                               2222080,2353152,2615296,3139584};

// ---------------- workspace layout (floats) ----------------
constexpr size_t OFF_RING = 0;          // 4,188,160 floats
constexpr size_t OFF_X    = 4188160;    // exchange: 4 slots * 512 f4

// ---------------- LDS pool offsets (floats) ----------------
#define P_WC     0        // [20][4][256]: row g: [0:128]=W0(prev) [128:256]=W1(res)
#define P_F      20480    // [19][4][128]
#define P_WST    30208    // [512]: [0:256]=res rows, [256:512]=skip rows
#define P_WSKIPC 30720    // [2][128]
#define P_WFC    30976    // [2][128]
#define P_WLOG   31232    // [4][128]
#define P_WF0    31744    // [128]
#define P_WF1    31872    // [128]
#define P_FB     32000    // [128]
#define P_CONDZ  32128    // [20][4][8]
#define P_SFC    32768    // [2][8]
#define P_RESB   32784    // [20][2]
#define P_SKIPB  32824    // [20][2]
#define P_ZB     32864    // [20][4]
#define P_LOGB   32944    // [4]
#define P_SKIPCB 32948    // [2]
#define P_Z0C    32950    // [4][6]
#define P_SKC    32974    // [2][3]
#define P_XS     32980    // [3][8]
#define P_SL     33004    // [32]
#define P_SKACC  33036    // [16]
#define P_R2     33052    // [16]
#define P_CF     33068    // [8][66]
#define P_PREVF  33596    // [8][132]          (16B aligned)
#define P_HF     34652    // [2][8][132] parity
#define P_RESF   36764    // [2][8][132] parity (buf0 holds res_0 at step start)
#define POOL_FL  38876    // 155,504 bytes -> 1 block/CU

// ---------------- coherent 16B exchange primitives (sc0 sc1 -> L3) ----------
__device__ __forceinline__ f4 ldx(const f4* p) {
    f4 r;
    asm volatile("global_load_dwordx4 %0, %1, off sc0 sc1\n\ts_waitcnt vmcnt(0)"
                 : "=v"(r) : "v"(p) : "memory");
    return r;
}
__device__ __forceinline__ void ldx2(const f4* p0, const f4* p1, f4& a, f4& b) {
    asm volatile("global_load_dwordx4 %0, %2, off sc0 sc1\n\t"
                 "global_load_dwordx4 %1, %3, off sc0 sc1\n\t"
                 "s_waitcnt vmcnt(0)"
                 : "=&v"(a), "=&v"(b) : "v"(p0), "v"(p1) : "memory");
}
__device__ __forceinline__ void stx(f4* p, f4 v) {
    asm volatile("global_store_dwordx4 %0, %1, off sc0 sc1"
                 :: "v"(p), "v"(v) : "memory");
}
__device__ __forceinline__ void spin(const f4* p, int e, f4& a) {
    while (__float_as_int(a.w) != e) a = ldx(p);
}

// ---- uniform mailbox: 8 f4 per block per exchange; f4 q = {v0, v1, 0, tag}
// from block Jb slot q: component i -> batch (2q+i)&7, column 2*Jb + (q>=4)
__device__ __forceinline__ void pub2(f4* slot, int J, int q, float v0, float v1, int e) {
    f4 v; v.x = v0; v.y = v1; v.z = 0.f; v.w = __int_as_float(e);
    stx(slot + J*8 + q, v);
}
__device__ __forceinline__ void scat2(float* dst, f4 v, int idx, bool dorelu) {
    int Jb = idx >> 3, q = idx & 7;
    float x = v.x, y = v.y;
    if (dorelu) { x = fmaxf(x, 0.f); y = fmaxf(y, 0.f); }
    if (q < 4) {
        dst[(2*q)*132 + 2*Jb]     = x;
        dst[(2*q+1)*132 + 2*Jb]   = y;
    } else {
        dst[(2*q-8)*132 + 2*Jb+1] = x;
        dst[(2*q-7)*132 + 2*Jb+1] = y;
    }
}
// 512 threads: exactly ONE f4 per thread
__device__ __forceinline__ void consume(const f4* slot, int e, float* dst, bool dorelu) {
    int m = threadIdx.x;
    const f4* p0 = slot + m;
    f4 a = ldx(p0);
    spin(p0, e, a);
    scat2(dst, a, m, dorelu);
}
__device__ __forceinline__ void consume_pair(const f4* sR, int eR, float* dR,
                                             const f4* sH, int eH, float* dH) {
    int m = threadIdx.x;
    const f4 *pr = sR + m, *ph = sH + m;
    f4 ra, ha;
    ldx2(pr, ph, ra, ha);
    spin(pr, eR, ra);
    scat2(dR, ra, m, false);
    spin(ph, eH, ha);
    scat2(dH, ha, m, false);
}

// ============================================================
__global__ __launch_bounds__(NTHR, 1) void wn_gen(
    const float* __restrict__ enc,
    const float* __restrict__ first_w,  const float* __restrict__ first_b,
    const float* __restrict__ causal_w, const float* __restrict__ causal_b,
    const float* __restrict__ cond_w,   const float* __restrict__ cond_b,
    const float* __restrict__ res_w,    const float* __restrict__ res_b,
    const float* __restrict__ skip_w,   const float* __restrict__ skip_b,
    const float* __restrict__ skipc_w,  const float* __restrict__ skipc_b,
    const float* __restrict__ fc_w,     const float* __restrict__ fc_b,
    const float* __restrict__ condf_w,  const float* __restrict__ condf_b,
    const float* __restrict__ logits_w, const float* __restrict__ logits_b,
    float* __restrict__ wsf, float* __restrict__ out)
{
    extern __shared__ float pool[];
    const int tid = threadIdx.x;
    const int J = blockIdx.x;
    float* ring = wsf + OFF_RING;
    f4* xb = (f4*)(wsf + OFF_X);

    // ---------------- init: weight slices -> LDS ----------------
    for (int m = tid; m < 20480; m += NTHR) {
        int l = m >> 10, rem = m & 1023, g = rem >> 8, i = rem & 255;
        int grow = (g < 2) ? (2*J + g) : (128 + 2*J + (g - 2));
        int col = i & 127, k = i >> 7;
        pool[P_WC + m] = causal_w[((size_t)(l*256 + grow)*128 + col)*2 + k];
    }
    if (tid < 256) {
        int r = tid >> 7, i = tid & 127;
        pool[P_WSKIPC + tid] = skipc_w[(size_t)(2*J + r)*128 + i];
        pool[P_WFC + tid]    = fc_w[(size_t)(2*J + r)*128 + i];
    }
    {
        int w2 = tid >> 7, i = tid & 127;
        pool[P_WLOG + tid] = logits_w[(size_t)(4*J + w2)*128 + i];
    }
    if (tid < 128) {
        pool[P_WF0 + tid] = first_w[2*tid];
        pool[P_WF1 + tid] = first_w[2*tid + 1];
        pool[P_FB + tid]  = first_b[tid];
    }
    if (tid < 40) {
        int l = tid >> 1, r = tid & 1;
        pool[P_RESB + tid]  = res_b[l*128 + 2*J + r];
        pool[P_SKIPB + tid] = skip_b[l*128 + 2*J + r];
    }
    if (tid < 4) pool[P_LOGB + tid] = logits_b[4*J + tid];
    if (tid < 2) pool[P_SKIPCB + tid] = skipc_b[2*J + tid];
    if (tid < 8) {
        pool[P_XS + tid]      = 128.f/255.f - 0.5f;  // X(0)
        pool[P_XS + 8 + tid]  = 0.f;                 // X(-1)
        pool[P_XS + 16 + tid] = 0.f;                 // X(-2)
    }
    __syncthreads();

    // F_l[g][j] = sum_i W1_{l+1}[g][i] * res_w[l][i][j]   (l = 0..18)
    for (int l = 0; l < 19; ++l) {
        for (int m = tid; m < 512; m += NTHR) {
            int g = m >> 7, j = m & 127;
            const float* w1 = pool + P_WC + ((l+1)*4 + g)*256 + 128;
            const float* rw = res_w + (size_t)l*128*128 + j;
            float acc = 0.f;
            #pragma unroll 8
            for (int i = 0; i < 128; ++i) acc += w1[i] * rw[(size_t)i*128];
            pool[P_F + (l*4 + g)*128 + j] = acc;
        }
    }
    // zb_l[g] = W1_l[g] . res_b[l-1]  (l >= 1)
    if (tid < 80) {
        int l = tid >> 2, g = tid & 3;
        float acc = 0.f;
        if (l >= 1) {
            const float* w1 = pool + P_WC + (l*4 + g)*256 + 128;
            for (int i = 0; i < 128; ++i) acc += w1[i] * res_b[(l-1)*128 + i];
        }
        pool[P_ZB + tid] = acc;
    }
    // layer-0 closed form: z0 = kf*KP + KC + x2*U + x1*C1 + x0*A0 + condz0
    if (tid < 4) {
        const float* w0 = pool + P_WC + tid*256;
        const float* w1 = w0 + 128;
        float kp = 0.f, kc = 0.f, u = 0.f, c1 = 0.f, a0 = 0.f;
        for (int j = 0; j < 128; ++j) {
            float f0 = pool[P_WF0 + j], f1 = pool[P_WF1 + j], fbv = pool[P_FB + j];
            kp += w0[j]*fbv; kc += w1[j]*fbv;
            u  += w0[j]*f0;  c1 += w0[j]*f1 + w1[j]*f0;  a0 += w1[j]*f1;
        }
        pool[P_Z0C + tid*6 + 0] = kp;
        pool[P_Z0C + tid*6 + 1] = kc;
        pool[P_Z0C + tid*6 + 2] = u;
        pool[P_Z0C + tid*6 + 3] = c1;
        pool[P_Z0C + tid*6 + 4] = a0;
    }
    // skip-init closed form: skip0 = SK + x1*SA + x0*SB
    if (tid < 2) {
        const float* wr = pool + P_WSKIPC + tid*128;
        float sk = pool[P_SKIPCB + tid], sa = 0.f, sb = 0.f;
        for (int j = 0; j < 128; ++j) {
            sk += wr[j]*pool[P_FB + j];
            sa += wr[j]*pool[P_WF0 + j];
            sb += wr[j]*pool[P_WF1 + j];
        }
        pool[P_SKC + tid*3 + 0] = sk;
        pool[P_SKC + tid*3 + 1] = sa;
        pool[P_SKC + tid*3 + 2] = sb;
    }
    __syncthreads();

    int e = 0;            // exchange epoch (uniform across all blocks)
    int er_pending = 0;   // epoch of most recent res publish
    int esk = 0;          // epoch of skip publish

    for (int t = 0; t < TT; ++t) {
        // ---------------- per-chunk precompute ----------------
        if ((t & 63) == 0) {
            int te = t >> 6;
            for (int m = tid; m < 512; m += NTHR) {
                int b = m >> 6, j = m & 63;
                pool[P_CF + b*66 + j] = enc[(size_t)b*512 + j*8 + te];
            }
            __syncthreads();
            for (int m = tid; m < 640; m += NTHR) {
                int l = m >> 5, rem = m & 31, g = rem >> 3, b = rem & 7;
                int grow = (g < 2) ? (2*J + g) : (128 + 2*J + (g - 2));
                float acc = causal_b[l*256 + grow] + cond_b[l*256 + grow]
                          + pool[P_ZB + l*4 + g];
                const float* cw = cond_w + (size_t)(l*256 + grow)*64;
                const float* cf = pool + P_CF + b*66;
                for (int j = 0; j < 64; ++j) acc += cw[j]*cf[j];
                pool[P_CONDZ + l*32 + g*8 + b] = acc;
            }
            if (tid < 16) {
                int r = tid >> 3, b = tid & 7, row = 2*J + r;
                float acc = fc_b[row] + condf_b[row];
                const float* cw = condf_w + (size_t)row*64;
                const float* cf = pool + P_CF + b*66;
                for (int j = 0; j < 64; ++j) acc += cw[j]*cf[j];
                pool[P_SFC + r*8 + b] = acc;
            }
            __syncthreads();
        }

        // ---------------- h_0 closed form + immediate in-wave publish ----------
        ++e; const int eh0 = e;
        if (tid < 16) {
            int r = tid & 1, b = tid >> 1;
            float kf  = (t >= 1) ? 1.f : 0.f;
            float x0v = pool[P_XS + b];
            float x1v = pool[P_XS + 8 + b];
            float x2v = pool[P_XS + 16 + b];
            const float* zc = pool + P_Z0C;
            int g0 = r, g1 = 2 + r;
            float zg = kf*zc[g0*6+0] + zc[g0*6+1] + x2v*zc[g0*6+2]
                     + x1v*zc[g0*6+3] + x0v*zc[g0*6+4] + pool[P_CONDZ + g0*8 + b];
            float zo = kf*zc[g1*6+0] + zc[g1*6+1] + x2v*zc[g1*6+2]
                     + x1v*zc[g1*6+3] + x0v*zc[g1*6+4] + pool[P_CONDZ + g1*8 + b];
            float h0v = (1.f/(1.f + expf(-zg))) * tanhf(zo);
            float hnb = __shfl_xor(h0v, 2);     // partner (r, b^1): tid distance 2
            if (!(b & 1))
                pub2(xb + (size_t)(eh0 & 3)*512, J, r*4 + (b >> 1), h0v, hnb, eh0);
        }
        // res_0 -> RESF buf0 (read at l=1 S1', parity matches)
        for (int m = tid; m < 1024; m += NTHR) {
            int b = m >> 7, r = m & 127;
            pool[P_RESF + b*132 + r] =
                pool[P_FB + r] + pool[P_XS + 8 + b]*pool[P_WF0 + r]
                               + pool[P_XS + b]    *pool[P_WF1 + r];
        }
        // skip init + r2 init (closed form)
        if (tid < 16) {
            int r = tid >> 3, b = tid & 7;
            float x0v = pool[P_XS + b], x1v = pool[P_XS + 8 + b];
            pool[P_SKACC + r*8 + b] = pool[P_SKC + r*3] + x1v*pool[P_SKC + r*3 + 1]
                                                        + x0v*pool[P_SKC + r*3 + 2];
            int row = 2*J + r;
            pool[P_R2 + r*8 + b] = pool[P_FB + row] + x1v*pool[P_WF0 + row]
                                                    + x0v*pool[P_WF1 + row];
        }

        // ---------------- layer loop: 2 barriers per layer ----------------
        for (int l = 0; l < LL; ++l) {
            const int par = l & 1;
            int ehh;
            if (l == 0) {
                ehh = eh0;
            } else {
                // S1': 16-lane dots, all 8 waves; in-wave h + publish
                ++e; ehh = e;
                const int wv_ = tid >> 6, lane = tid & 63;
                const int r = wv_ & 1, bp = wv_ >> 1;
                const int half = lane >> 5, b2 = (lane >> 4) & 1, k = lane & 15;
                const int b = bp*2 + b2, g = half*2 + r;
                const float* wz = pool + P_WC + (l*4 + g)*256;
                const float* fm = pool + P_F + ((l-1)*4 + g)*128;
                const float* pv = pool + P_PREVF + b*132;
                const float* rs = pool + P_RESF + (par^1)*1056 + b*132;
                const float* hh = pool + P_HF + (par^1)*1056 + b*132;
                float acc = 0.f;
                #pragma unroll
                for (int i = 0; i < 8; ++i) {
                    int j = k + 16*i;
                    acc += wz[j]*pv[j] + wz[128 + j]*rs[j] + fm[j]*hh[j];
                }
                acc += __shfl_xor(acc,1); acc += __shfl_xor(acc,2);
                acc += __shfl_xor(acc,4); acc += __shfl_xor(acc,8);
                acc += pool[P_CONDZ + l*32 + g*8 + b];
                float zp = __shfl_xor(acc, 32);               // gate<->out half
                float zg = half ? zp : acc;
                float zo = half ? acc : zp;
                float h  = (1.f/(1.f + expf(-zg))) * tanhf(zo);
                float hnb = __shfl_xor(h, 16);                // batch pair b2^1
                if (half == 0 && k == 0 && b2 == 0)
                    pub2(xb + (size_t)(ehh & 3)*512, J, r*4 + bp, h, hnb, ehh);
            }
            // S6: stage res/skip weight rows (one float/thread)
            float wv0;
            {
                int r0 = (tid >> 7) & 1, i0 = tid & 127;
                const float* src = (tid < 256) ? res_w : skip_w;
                wv0 = src[(size_t)(l*128 + 2*J + r0)*128 + i0];
            }
            // S7: ring prefetch prev_{l+1} (2 floats/thread)
            ull pf = 0;
            if (l <= 18) {
                int d = c_dil[l+1];
                if (t >= d) {
                    int slot = (t - d) & (2*d - 1);
                    pf = __hip_atomic_load((const ull*)(ring + c_roff[l+1]
                             + (size_t)slot*1024 + tid*2),
                             __ATOMIC_RELAXED, __HIP_MEMORY_SCOPE_AGENT);
                }
            }
            // S8: consume into parity buffers
            if (l == 0) {
                consume(xb + (size_t)(ehh & 3)*512, ehh, pool + P_HF, false);
            } else if (l <= 18) {
                consume_pair(xb + (size_t)(er_pending & 3)*512, er_pending,
                             pool + P_RESF + par*1056,
                             xb + (size_t)(ehh & 3)*512, ehh,
                             pool + P_HF + par*1056);
            } else {
                consume(xb + (size_t)(ehh & 3)*512, ehh, pool + P_HF + par*1056, false);
            }
            // S8.5: land staged weight rows
            pool[P_WST + tid] = wv0;
            __syncthreads();   // bar A
            // S10: 16-lane dots; res = waves 0-3, skip = waves 4-7; register publish
            {
                const int lane = tid & 63, k = lane & 15, bq = lane >> 4;
                const int w4 = (tid >> 6) & 3, r = w4 & 1, role = tid >> 8;
                const int b = (w4 >> 1)*4 + bq;
                if (role == 1 || l <= 18) {
                    const float* wr = pool + P_WST + role*256 + r*128;
                    const float* hh = pool + P_HF + par*1056 + b*132;
                    float acc = 0.f;
                    #pragma unroll
                    for (int i = 0; i < 8; ++i) { int j = k + 16*i; acc += wr[j]*hh[j]; }
                    acc += __shfl_xor(acc,1); acc += __shfl_xor(acc,2);
                    acc += __shfl_xor(acc,4); acc += __shfl_xor(acc,8);
                    if (role == 1) {
                        float v = pool[P_SKACC + r*8 + b] + acc + pool[P_SKIPB + l*2 + r];
                        if (k == 0) pool[P_SKACC + r*8 + b] = v;
                        if (l == 19) {
                            float vnb = __shfl_xor(v, 16);
                            if (k == 0 && !(b & 1))
                                pub2(xb + (size_t)((e+1) & 3)*512, J,
                                     r*4 + (b >> 1), v, vnb, e + 1);
                        }
                    } else {
                        float v = pool[P_R2 + r*8 + b] + acc + pool[P_RESB + l*2 + r];
                        if (k == 0) {
                            pool[P_R2 + r*8 + b] = v;
                            int d = c_dil[l+1];
                            int slot = t & (2*d - 1);
                            __hip_atomic_store(ring + c_roff[l+1] + (size_t)slot*1024
                                                   + b*128 + 2*J + r,
                                               v, __ATOMIC_RELAXED, __HIP_MEMORY_SCOPE_AGENT);
                        }
                        if (l <= 17) {
                            float vnb = __shfl_xor(v, 16);
                            if (k == 0 && !(b & 1))
                                pub2(xb + (size_t)((e+1) & 3)*512, J,
                                     r*4 + (b >> 1), v, vnb, e + 1);
                        }
                    }
                }
            }
            if (l <= 17)      { ++e; er_pending = e; }
            else if (l == 19) { ++e; esk = e; }
            // S11: land prev prefetch
            if (l <= 18) {
                int b = tid >> 6, c = (tid & 63)*2;
                union { ull u; float f[2]; } u0; u0.u = pf;
                pool[P_PREVF + b*132 + c]     = u0.f[0];
                pool[P_PREVF + b*132 + c + 1] = u0.f[1];
            }
            __syncthreads();   // bar B
        }

        // ---------------- head ----------------
        consume(xb + (size_t)(esk & 3)*512, esk, pool + P_HF, false);   // skip -> HF buf0
        __syncthreads();
        // fc: s = relu(skip).fc^T + sfc  (waves 0-3, 16-lane dots), in-wave publish
        ++e;
        if (tid < 256) {
            int r = (tid >> 7) & 1, b = (tid >> 4) & 7, k = tid & 15;
            const float* wr = pool + P_WFC + r*128;
            const float* sk = pool + P_HF + b*132;
            float acc = 0.f;
            #pragma unroll
            for (int i = 0; i < 8; ++i) { int j = k + 16*i; acc += wr[j]*fmaxf(sk[j], 0.f); }
            acc += __shfl_xor(acc,1); acc += __shfl_xor(acc,2);
            acc += __shfl_xor(acc,4); acc += __shfl_xor(acc,8);
            float v = acc + pool[P_SFC + r*8 + b];
            float vnb = __shfl_xor(v, 16);
            if (k == 0 && !(b & 1))
                pub2(xb + (size_t)(e & 3)*512, J, r*4 + (b >> 1), v, vnb, e);
        }
        consume(xb + (size_t)(e & 3)*512, e, pool + P_RESF, true);   // relu(s) -> RESF buf0
        __syncthreads();
        // logits: wave = batch, 16-lane dots; out-store + block-local argmax pair
        {
            int b = tid >> 6, g = (tid >> 4) & 3, k = tid & 15;
            const float* wr = pool + P_WLOG + g*128;
            const float* sv = pool + P_RESF + b*132;
            float acc = 0.f;
            #pragma unroll
            for (int i = 0; i < 8; ++i) { int j = k + 16*i; acc += wr[j]*sv[j]; }
            acc += __shfl_xor(acc,1); acc += __shfl_xor(acc,2);
            acc += __shfl_xor(acc,4); acc += __shfl_xor(acc,8);
            float v = acc + pool[P_LOGB + g];
            float best = (k == 0) ? v : -3.4e38f;
            int bi = 4*J + g;
            { float ov = __shfl_xor(best, 16); int oi = __shfl_xor(bi, 16);
              if (ov > best || (ov == best && oi < bi)) { best = ov; bi = oi; } }
            { float ov = __shfl_xor(best, 32); int oi = __shfl_xor(bi, 32);
              if (ov > best || (ov == best && oi < bi)) { best = ov; bi = oi; } }
            if (k == 0) out[4096 + ((size_t)(t*BB + b))*256 + 4*J + g] = v;
            if ((tid & 63) == 0) { pool[P_SL + 2*b] = best; pool[P_SL + 2*b + 1] = (float)bi; }
        }
        __syncthreads();
        ++e;
        // argmax pairs: q<4 -> max pairs, q>=4 -> idx pairs
        if (tid < 8) {
            int q = tid;
            float v0, v1;
            if (q < 4) { v0 = pool[P_SL + 4*q];         v1 = pool[P_SL + 4*q + 2]; }
            else       { v0 = pool[P_SL + 4*(q-4) + 1]; v1 = pool[P_SL + 4*(q-4) + 3]; }
            pub2(xb + (size_t)(e & 3)*512, J, q, v0, v1, e);
        }
        consume(xb + (size_t)(e & 3)*512, e, pool + P_HF, false);    // -> HF buf0
        __syncthreads();
        // final argmax reduce (idx-min tie-break == global first max) + x shift
        if (tid < 64) {
            int b = tid >> 3, j0 = tid & 7;
            float best = -3.4e38f; float bidx = 0.f;
            #pragma unroll
            for (int k2 = 0; k2 < 8; ++k2) {
                int j = j0*8 + k2;
                float v  = pool[P_HF + b*132 + 2*j];
                float id = pool[P_HF + b*132 + 2*j + 1];
                if (v > best || (v == best && id < bidx)) { best = v; bidx = id; }
            }
            #pragma unroll
            for (int m = 4; m >= 1; m >>= 1) {
                float ov = __shfl_xor(best, m); float oi = __shfl_xor(bidx, m);
                if (ov > best || (ov == best && oi < bidx)) { best = ov; bidx = oi; }
            }
            if (j0 == 0) {
                if (J == 0) out[t*BB + b] = bidx;
                pool[P_XS + 16 + b] = pool[P_XS + 8 + b];
                pool[P_XS + 8 + b]  = pool[P_XS + b];
                pool[P_XS + b]      = bidx*(1.f/255.f) - 0.5f;
            }
        }
        __syncthreads();
    }
}

// ============================================================
extern "C" void kernel_launch(void* const* d_in, const int* in_sizes, int n_in,
                              void* d_out, int out_size, void* d_ws, size_t ws_size,
                              hipStream_t stream) {
    const float* enc      = (const float*)d_in[0];
    const float* first_w  = (const float*)d_in[1];
    const float* first_b  = (const float*)d_in[2];
    const float* causal_w = (const float*)d_in[3];
    const float* causal_b = (const float*)d_in[4];
    const float* cond_w   = (const float*)d_in[5];
    const float* cond_b   = (const float*)d_in[6];
    const float* res_w    = (const float*)d_in[7];
    const float* res_b    = (const float*)d_in[8];
    const float* skip_w   = (const float*)d_in[9];
    const float* skip_b   = (const float*)d_in[10];
    const float* skipc_w  = (const float*)d_in[11];
    const float* skipc_b  = (const float*)d_in[12];
    const float* fc_w     = (const float*)d_in[13];
    const float* fc_b     = (const float*)d_in[14];
    const float* condf_w  = (const float*)d_in[15];
    const float* condf_b  = (const float*)d_in[16];
    const float* logits_w = (const float*)d_in[17];
    const float* logits_b = (const float*)d_in[18];

    float* wsf = (float*)d_ws;
    float* out = (float*)d_out;

    wn_gen<<<NBLK, NTHR, POOL_FL*4, stream>>>(
        enc, first_w, first_b, causal_w, causal_b, cond_w, cond_b,
        res_w, res_b, skip_w, skip_b, skipc_w, skipc_b, fc_w, fc_b,
        condf_w, condf_b, logits_w, logits_b, wsf, out);
}